// Round 13
// baseline (543.844 us; speedup 1.0000x reference)
//
#include <hip/hip_runtime.h>

typedef unsigned short u16;
typedef unsigned int   u32;
typedef unsigned char  u8;

using bf16x8 = __attribute__((ext_vector_type(8))) short;  // 8 bf16 in 4 VGPRs
using f32x4  = __attribute__((ext_vector_type(4))) float;
using i32x4  = __attribute__((ext_vector_type(4))) int;    // 16 i8 operand / i32 acc

__device__ __forceinline__ float bf2f(u16 h) {
  u32 u = ((u32)h) << 16;
  return __builtin_bit_cast(float, u);
}
__device__ __forceinline__ u16 f2bf(float f) {   // round-to-nearest-even
  u32 u = __builtin_bit_cast(u32, f);
  u += 0x7fffu + ((u >> 16) & 1u);
  return (u16)(u >> 16);
}

__device__ __forceinline__ void gload16(const void* src, void* ldsdst) {
  __builtin_amdgcn_global_load_lds(
      (const __attribute__((address_space(1))) void*)src,
      (__attribute__((address_space(3))) void*)ldsdst, 16, 0, 0);
}

// i8 MFMA via inline asm (ISA 10: v_mfma_i32_16x16x64_i8)
__device__ __forceinline__ void mfma_i8(i32x4& c, i32x4 a, i32x4 b) {
  asm volatile("v_mfma_i32_16x16x64_i8 %0, %1, %2, %0" : "+a"(c) : "v"(a), "v"(b));
}

// m204 bijective XCD swizzle
__device__ __forceinline__ int xcd_swz(int wg, int nwg) {
  int q = nwg >> 3, r = nwg & 7, xcd = wg & 7, loc = wg >> 3;
  return (xcd < r ? xcd * (q + 1) : r * (q + 1) + (xcd - r) * q) + loc;
}

// ---------------------------------------------------------------------------
// per-row (over K=1024) signed-i8 quantization of an f32 matrix (wave/row)
__global__ __launch_bounds__(256) void cvt_w_i8(const float* __restrict__ in,
                                                u8* __restrict__ out,
                                                float* __restrict__ sc) {
  const int row  = blockIdx.x * 4 + (threadIdx.x >> 6);
  const int lane = threadIdx.x & 63;
  const float4* p = (const float4*)(in + (size_t)row * 1024 + lane * 16);
  float v[16];
  float mx = 0.f;
#pragma unroll
  for (int i = 0; i < 4; ++i) {
    float4 t = p[i];
    v[i * 4 + 0] = t.x; v[i * 4 + 1] = t.y; v[i * 4 + 2] = t.z; v[i * 4 + 3] = t.w;
#pragma unroll
    for (int j = 0; j < 4; ++j) mx = fmaxf(mx, fabsf(v[i * 4 + j]));
  }
#pragma unroll
  for (int m = 1; m < 64; m <<= 1) mx = fmaxf(mx, __shfl_xor(mx, m));
  const float scale = mx > 0.f ? 127.f / mx : 0.f;
  u32 pk[4];
#pragma unroll
  for (int i = 0; i < 4; ++i) {
    u32 b0 = (u32)(__float2int_rn(v[i * 4 + 0] * scale) & 0xff);
    u32 b1 = (u32)(__float2int_rn(v[i * 4 + 1] * scale) & 0xff);
    u32 b2 = (u32)(__float2int_rn(v[i * 4 + 2] * scale) & 0xff);
    u32 b3 = (u32)(__float2int_rn(v[i * 4 + 3] * scale) & 0xff);
    pk[i] = b0 | (b1 << 8) | (b2 << 16) | (b3 << 24);
  }
  *(uint4*)(out + (size_t)row * 1024 + lane * 16) = make_uint4(pk[0], pk[1], pk[2], pk[3]);
  if (lane == 0) sc[row] = mx > 0.f ? mx / 127.f : 0.f;
}

// ---------------------------------------------------------------------------
// per-row signed-i8 quantization of a bf16 matrix (wave/row) — attn output
__global__ __launch_bounds__(256) void quant_i8(const u16* __restrict__ in,
                                                u8* __restrict__ out,
                                                float* __restrict__ sc) {
  const int row  = blockIdx.x * 4 + (threadIdx.x >> 6);
  const int lane = threadIdx.x & 63;
  const u16* p = in + (size_t)row * 1024 + lane * 16;
  float v[16];
  float mx = 0.f;
#pragma unroll
  for (int i = 0; i < 2; ++i) {
    bf16x8 t = *(const bf16x8*)(p + i * 8);
#pragma unroll
    for (int j = 0; j < 8; ++j) {
      float f = bf2f((u16)t[j]);
      v[i * 8 + j] = f;
      mx = fmaxf(mx, fabsf(f));
    }
  }
#pragma unroll
  for (int m = 1; m < 64; m <<= 1) mx = fmaxf(mx, __shfl_xor(mx, m));
  const float scale = mx > 0.f ? 127.f / mx : 0.f;
  u32 pk[4];
#pragma unroll
  for (int i = 0; i < 4; ++i) {
    u32 b0 = (u32)(__float2int_rn(v[i * 4 + 0] * scale) & 0xff);
    u32 b1 = (u32)(__float2int_rn(v[i * 4 + 1] * scale) & 0xff);
    u32 b2 = (u32)(__float2int_rn(v[i * 4 + 2] * scale) & 0xff);
    u32 b3 = (u32)(__float2int_rn(v[i * 4 + 3] * scale) & 0xff);
    pk[i] = b0 | (b1 << 8) | (b2 << 16) | (b3 << 24);
  }
  *(uint4*)(out + (size_t)row * 1024 + lane * 16) = make_uint4(pk[0], pk[1], pk[2], pk[3]);
  if (lane == 0) sc[row] = mx > 0.f ? mx / 127.f : 0.f;
}

// ---------------------------------------------------------------------------
// h row (1024) per wave: h = relu(x*W+b), per-row max, quantize to i8 [0,127]
__global__ __launch_bounds__(256) void hgen_i8(const float* __restrict__ x,
                                               const float* __restrict__ W,
                                               const float* __restrict__ bias,
                                               u8* __restrict__ h, float* __restrict__ hsc,
                                               int F, int logF, int b0, int xstride) {
  const int row  = blockIdx.x * 4 + (threadIdx.x >> 6);
  const int lane = threadIdx.x & 63;
  const int f = row & (F - 1);
  const int b = b0 + (row >> logF);
  const float xv = x[(size_t)b * xstride + f];
  const float4* wp = (const float4*)(W + (size_t)f * 1024 + lane * 16);
  const float4* bp = (const float4*)(bias + (size_t)f * 1024 + lane * 16);
  float hv[16];
  float mx = 0.f;
#pragma unroll
  for (int i = 0; i < 4; ++i) {
    float4 wv = wp[i];
    float4 bv = bp[i];
    hv[i * 4 + 0] = fmaxf(xv * wv.x + bv.x, 0.f);
    hv[i * 4 + 1] = fmaxf(xv * wv.y + bv.y, 0.f);
    hv[i * 4 + 2] = fmaxf(xv * wv.z + bv.z, 0.f);
    hv[i * 4 + 3] = fmaxf(xv * wv.w + bv.w, 0.f);
#pragma unroll
    for (int j = 0; j < 4; ++j) mx = fmaxf(mx, hv[i * 4 + j]);
  }
#pragma unroll
  for (int m = 1; m < 64; m <<= 1) mx = fmaxf(mx, __shfl_xor(mx, m));
  const float scale = mx > 0.f ? 127.f / mx : 0.f;
  u32 pk[4];
#pragma unroll
  for (int i = 0; i < 4; ++i) {
    u32 q0 = (u32)__float2int_rn(hv[i * 4 + 0] * scale);
    u32 q1 = (u32)__float2int_rn(hv[i * 4 + 1] * scale);
    u32 q2 = (u32)__float2int_rn(hv[i * 4 + 2] * scale);
    u32 q3 = (u32)__float2int_rn(hv[i * 4 + 3] * scale);
    pk[i] = q0 | (q1 << 8) | (q2 << 16) | (q3 << 24);
  }
  *(uint4*)(h + (size_t)row * 1024 + lane * 16) = make_uint4(pk[0], pk[1], pk[2], pk[3]);
  if (lane == 0) hsc[row] = mx > 0.f ? mx / 127.f : 0.f;
}

// ---------------------------------------------------------------------------
// i8 GEMM: C(MxN,bf16) = sA[m]*sB[n]*(qA . qB^T) + bias(N)
// 256x128 tile, BK=64 i8, 8 waves 4Mx2N, triple-buffered, counted vmcnt(3).
// STATS: atomically accumulate per-row (sum, sumsq) into stats[row].
template <bool STATS>
__global__ __launch_bounds__(512, 4) void gemm_i8(const u8* __restrict__ A,
                                                  const u8* __restrict__ B,
                                                  const float* __restrict__ sAsc,
                                                  const float* __restrict__ sBsc,
                                                  const float* __restrict__ bias,
                                                  u16* __restrict__ C,
                                                  float2* __restrict__ stats,
                                                  int M, int N, int K) {
  __shared__ u8 sA[3][256 * 64];
  __shared__ u8 sB[3][128 * 64];
  const int tid  = threadIdx.x;
  const int lane = tid & 63;
  const int w    = tid >> 6;
  const int wm   = w >> 1;
  const int wn   = w & 1;

  const int nwg = gridDim.x * gridDim.y;
  const int wg  = blockIdx.y * gridDim.x + blockIdx.x;
  const int swz = xcd_swz(wg, nwg);
  const int n0 = (swz % gridDim.x) * 128;
  const int m0 = (swz / gridDim.x) * 256;

  i32x4 acc[4][4] = {};

  const int r_in  = lane >> 2;
  const int s_src = (lane & 3) ^ ((lane >> 3) & 3);

  auto stage = [&](int kt, int b) {
    const int k0 = kt << 6;
    gload16(A + (size_t)(m0 + w * 16 + r_in) * K + k0 + s_src * 16, &sA[b][w * 1024]);
    gload16(A + (size_t)(m0 + (w + 8) * 16 + r_in) * K + k0 + s_src * 16, &sA[b][(w + 8) * 1024]);
    gload16(B + (size_t)(n0 + w * 16 + r_in) * K + k0 + s_src * 16, &sB[b][w * 1024]);
  };

  const int NT = K >> 6;
  stage(0, 0);
  stage(1, 1);
  asm volatile("s_waitcnt vmcnt(3)" ::: "memory");
  __builtin_amdgcn_s_barrier();

  int cur = 0, nx = 2;
  for (int t = 0; t < NT; ++t) {
    const bool more = (t + 2 < NT);
    if (more) stage(t + 2, nx);

    i32x4 af[4], bg[4];
    const int g = lane >> 4;
#pragma unroll
    for (int mf = 0; mf < 4; ++mf) {
      int ra = wm * 64 + mf * 16 + (lane & 15);
      af[mf] = *(const i32x4*)(&sA[cur][ra * 64 + ((g ^ ((ra >> 1) & 3)) * 16)]);
    }
#pragma unroll
    for (int nf = 0; nf < 4; ++nf) {
      int rb = wn * 64 + nf * 16 + (lane & 15);
      bg[nf] = *(const i32x4*)(&sB[cur][rb * 64 + ((g ^ ((rb >> 1) & 3)) * 16)]);
    }
    asm volatile("s_waitcnt lgkmcnt(0)" ::: "memory");
    __builtin_amdgcn_sched_barrier(0);
    __builtin_amdgcn_s_setprio(1);
#pragma unroll
    for (int mf = 0; mf < 4; ++mf)
#pragma unroll
      for (int nf = 0; nf < 4; ++nf)
        mfma_i8(acc[mf][nf], af[mf], bg[nf]);
    __builtin_amdgcn_s_setprio(0);
    if (more) asm volatile("s_waitcnt vmcnt(3)" ::: "memory");
    else      asm volatile("s_waitcnt vmcnt(0)" ::: "memory");
    __builtin_amdgcn_s_barrier();
    cur = (cur == 2) ? 0 : cur + 1;
    nx  = (nx  == 2) ? 0 : nx  + 1;
  }

  // epilogue: D layout col = lane&15, row = (lane>>4)*4 + reg; de-scale rank-1
  float sb4[4], bs4[4];
#pragma unroll
  for (int nf = 0; nf < 4; ++nf) {
    int cl = n0 + wn * 64 + nf * 16 + (lane & 15);
    sb4[nf] = sBsc[cl];
    bs4[nf] = bias[cl];
  }
#pragma unroll
  for (int mf = 0; mf < 4; ++mf) {
    int r0 = m0 + wm * 64 + mf * 16 + (lane >> 4) * 4;
    float4 sa4 = *(const float4*)(sAsc + r0);
    const float* sap = (const float*)&sa4;
#pragma unroll
    for (int reg = 0; reg < 4; ++reg) {
      float s = 0.f, s2 = 0.f;
#pragma unroll
      for (int nf = 0; nf < 4; ++nf) {
        int cl = n0 + wn * 64 + nf * 16 + (lane & 15);
        float v = (float)acc[mf][nf][reg] * (sap[reg] * sb4[nf]) + bs4[nf];
        C[(size_t)(r0 + reg) * N + cl] = f2bf(v);
        if (STATS) { s += v; s2 += v * v; }
      }
      if (STATS) {
#pragma unroll
        for (int m = 1; m < 16; m <<= 1) { s += __shfl_xor(s, m); s2 += __shfl_xor(s2, m); }
        if ((lane & 15) == 0) {
          atomicAdd(&stats[r0 + reg].x, s);
          atomicAdd(&stats[r0 + reg].y, s2);
        }
      }
    }
  }
}

// finalize LN stats: (sum, sumsq) -> (mu, rsqrt(var+eps))
__global__ __launch_bounds__(256) void ln_fin(float2* __restrict__ stats, int n) {
  int i = blockIdx.x * 256 + threadIdx.x;
  if (i >= n) return;
  float2 s = stats[i];
  float mu  = s.x * (1.f / 1024.f);
  float var = s.y * (1.f / 1024.f) - mu * mu;
  stats[i] = make_float2(mu, rsqrtf(var + 1e-5f));
}

// ---------------------------------------------------------------------------
// Fused attention, QBLK = F (one block per (head, batch)).
// (1024,1): guarantee 128 VGPRs/wave (implicit bound gave 64 -> spill risk).
__global__ __launch_bounds__(1024, 1) void attn(const u16* __restrict__ qkv,
                                                u16* __restrict__ o_out, int F) {
  __shared__ u16 k_lds[64 * 136];
  __shared__ u16 vT[128 * 72];        // [128 d][64+8 kpos], col-swizzled
  __shared__ u16 p_lds[16 * 16 * 72]; // per-wave [16 qrow][64+8 kpos]

  const int tid  = threadIdx.x;
  const int lane = tid & 63;
  const int w    = tid >> 6;
  const int nt   = blockDim.x;

  const int head = blockIdx.x & 7;
  const int bc   = blockIdx.x >> 3;

  const size_t rowbase = (size_t)bc * F * 3072;
  const float scale = 0.12751744865678818f;   // log2(e)/sqrt(128)

  const int qr = lane & 15;
  const int g4 = lane >> 4;

  // Q fragments in registers: row (w*16 + qr), 16B slices kk*32+8*g4
  bf16x8 qreg[4];
  {
    const u16* qsrc = qkv + rowbase + (size_t)(w * 16 + qr) * 3072 + head * 128;
#pragma unroll
    for (int kk = 0; kk < 4; ++kk) {
      bf16x8 v = *(const bf16x8*)(qsrc + kk * 32 + 8 * g4);
#pragma unroll
      for (int j = 0; j < 8; ++j) v[j] = (short)f2bf(bf2f((u16)v[j]) * scale);
      qreg[kk] = v;
    }
  }

  f32x4 o_acc[8] = {};
  float m_run = -INFINITY, l_run = 0.f;

  const int nkb = F >> 6;
  for (int kb = 0; kb < nkb; ++kb) {
    __syncthreads();   // prev compute done with k_lds/vT
    const u16* ksrc = qkv + rowbase + (size_t)(kb * 64) * 3072 + 1024 + head * 128;
    const u16* vsrc = ksrc + 1024;
    for (int it = tid; it < 1024; it += nt) {
      int r = it >> 4, s = it & 15;
      *(bf16x8*)(k_lds + r * 136 + s * 8) = *(const bf16x8*)(ksrc + (size_t)r * 3072 + s * 8);
    }
    for (int it = tid; it < 512; it += nt) {
      int g2 = it >> 4, s = it & 15;
      const u16* v0 = vsrc + (size_t)(2 * g2) * 3072 + s * 8;
      bf16x8 a = *(const bf16x8*)(v0);
      bf16x8 b = *(const bf16x8*)(v0 + 3072);
      int rs0 = (2 * g2) ^ ((s & 7) << 3);
      int d0  = s * 8;
#pragma unroll
      for (int j = 0; j < 8; ++j) {
        u32 pk = (u32)(u16)a[j] | ((u32)(u16)b[j] << 16);
        *(u32*)(vT + (d0 + j) * 72 + rs0) = pk;
      }
    }
    __syncthreads();

    // S^T (64 kpos x 16 qrows): A = k rows, B = q^T (registers)
    f32x4 sa[4] = {};
#pragma unroll
    for (int kk = 0; kk < 4; ++kk) {
#pragma unroll
      for (int f = 0; f < 4; ++f) {
        bf16x8 ak = *(const bf16x8*)(k_lds + (f * 16 + qr) * 136 + kk * 32 + 8 * g4);
        sa[f] = __builtin_amdgcn_mfma_f32_16x16x32_bf16(ak, qreg[kk], sa[f], 0, 0, 0);
      }
    }

    float tmax = -INFINITY;
#pragma unroll
    for (int f = 0; f < 4; ++f)
#pragma unroll
      for (int rr = 0; rr < 4; ++rr) tmax = fmaxf(tmax, sa[f][rr]);
    tmax = fmaxf(tmax, __shfl_xor(tmax, 16));
    tmax = fmaxf(tmax, __shfl_xor(tmax, 32));

    // defer-max (T13): skip rescale while the running max is still adequate
    const bool ns = !__all(tmax - m_run <= 8.f);
    float mnew = m_run, alpha = 1.f;
    if (ns) { mnew = fmaxf(m_run, tmax); alpha = exp2f(m_run - mnew); }

    float psum = 0.f;
#pragma unroll
    for (int f = 0; f < 4; ++f) {
      u16 pp[4];
#pragma unroll
      for (int rr = 0; rr < 4; ++rr) {
        float p = exp2f(sa[f][rr] - mnew);
        psum += p;
        pp[rr] = f2bf(p);
      }
      uint2 u;
      u.x = (u32)pp[0] | ((u32)pp[1] << 16);
      u.y = (u32)pp[2] | ((u32)pp[3] << 16);
      *(uint2*)(p_lds + w * 1152 + qr * 72 + f * 16 + g4 * 4) = u;
    }
    psum += __shfl_xor(psum, 16);
    psum += __shfl_xor(psum, 32);
    l_run = l_run * alpha + psum;
    m_run = mnew;

    if (ns) {
#pragma unroll
      for (int rr = 0; rr < 4; ++rr) {
        float ar = __shfl(alpha, g4 * 4 + rr);
#pragma unroll
        for (int g = 0; g < 8; ++g) o_acc[g][rr] *= ar;
      }
    }

#pragma unroll
    for (int kk2 = 0; kk2 < 2; ++kk2) {
      bf16x8 pa = *(const bf16x8*)(p_lds + w * 1152 + qr * 72 + kk2 * 32 + 8 * g4);
#pragma unroll
      for (int g = 0; g < 8; ++g) {
        int swv = ((g * 2 + (qr >> 3)) & 7) << 3;
        bf16x8 vb = *(const bf16x8*)(vT + (g * 16 + qr) * 72 + ((kk2 * 32 + 8 * g4) ^ swv));
        o_acc[g] = __builtin_amdgcn_mfma_f32_16x16x32_bf16(pa, vb, o_acc[g], 0, 0, 0);
      }
    }
  }

  float linv = 1.f / l_run;
#pragma unroll
  for (int rr = 0; rr < 4; ++rr) {
    float lr = __shfl(linv, g4 * 4 + rr);
    size_t row = (size_t)bc * F + w * 16 + g4 * 4 + rr;
#pragma unroll
    for (int g = 0; g < 8; ++g)
      o_out[row * 1024 + head * 128 + g * 16 + qr] = f2bf(o_acc[g][rr] * lr);
  }
}

// ---------------------------------------------------------------------------
__global__ __launch_bounds__(256) void ln_accum(const u16* __restrict__ proj,
                                                const float2* __restrict__ stats,
                                                const float* __restrict__ g,
                                                const float* __restrict__ beta,
                                                float* __restrict__ dp, int F, int b0) {
  int d  = blockIdx.x * 256 + threadIdx.x;
  int bc = blockIdx.z;
  int f0 = blockIdx.y * 64;
  const u16* base = proj + ((size_t)(bc * F + f0)) * 1024 + d;
  const float2* st = stats + bc * F + f0;
  float acc = 0.f;
  for (int f = 0; f < 64; ++f) {
    float2 s = st[f];
    acc += (bf2f(base[(size_t)f * 1024]) - s.x) * s.y;
  }
  acc = acc * g[d] + 64.f * beta[d];
  atomicAdd(&dp[(size_t)(b0 + bc) * 1024 + d], acc);
}

// ---------------------------------------------------------------------------
__global__ __launch_bounds__(256) void cosine_sig(const float* __restrict__ dp,
                                                  const float* __restrict__ tp,
                                                  float* __restrict__ out) {
  __shared__ float red[3][4];
  int b = blockIdx.x;
  int tid = threadIdx.x, lane = tid & 63, w = tid >> 6;
  float dot = 0.f, n1 = 0.f, n2 = 0.f;
  for (int i = tid; i < 1024; i += 256) {
    float a = dp[(size_t)b * 1024 + i], c = tp[(size_t)b * 1024 + i];
    dot += a * c; n1 += a * a; n2 += c * c;
  }
#pragma unroll
  for (int m = 1; m < 64; m <<= 1) {
    dot += __shfl_xor(dot, m); n1 += __shfl_xor(n1, m); n2 += __shfl_xor(n2, m);
  }
  if (lane == 0) { red[0][w] = dot; red[1][w] = n1; red[2][w] = n2; }
  __syncthreads();
  if (tid == 0) {
    dot = red[0][0] + red[0][1] + red[0][2] + red[0][3];
    n1  = red[1][0] + red[1][1] + red[1][2] + red[1][3];
    n2  = red[2][0] + red[2][1] + red[2][2] + red[2][3];
    float denom = fmaxf(sqrtf(n1) * sqrtf(n2), 1e-8f);
    out[b] = 1.f / (1.f + __expf(-dot / denom));
  }
}

// ---------------------------------------------------------------------------
extern "C" void kernel_launch(void* const* d_in, const int* in_sizes, int n_in,
                              void* d_out, int out_size, void* d_ws, size_t ws_size,
                              hipStream_t stream) {
  const float* drug   = (const float*)d_in[0];
  const float* target = (const float*)d_in[1];

  char* p = (char*)d_ws;
  auto alloc = [&](size_t bytes) -> char* {
    char* r = p; p += (bytes + 255) & ~(size_t)255; return r;
  };

  u8*    w8_d    = (u8*)alloc((size_t)3072 * 1024);
  float* wsc_d   = (float*)alloc((size_t)3072 * 4);
  u8*    w8_t    = (u8*)alloc((size_t)3072 * 1024);
  float* wsc_t   = (float*)alloc((size_t)3072 * 4);
  u8*    w8o_d   = (u8*)alloc((size_t)1024 * 1024);
  float* wsco_d  = (float*)alloc((size_t)1024 * 4);
  u8*    w8o_t   = (u8*)alloc((size_t)1024 * 1024);
  float* wsco_t  = (float*)alloc((size_t)1024 * 4);
  float* dp      = (float*)alloc((size_t)2 * 128 * 1024 * 4);
  float* tp      = dp + 128 * 1024;

  // per-batch-unit scratch (PROJBUF OVERLAYS QKVBUF — qkvbuf dead after attn,
  // projbuf written by out-proj two dispatches later; stream serializes):
  //   h8 (reused as o8) + hsc + qkvbuf(=projbuf) + obuf + stats
  size_t fixed = (size_t)(p - (char*)d_ws);
  size_t per = (size_t)256 * 1024               /* h8 / o8 */
             + (size_t)256 * 4 + 256            /* hsc / osc */
             + (size_t)256 * 3072 * 2 + 256     /* qkvbuf (+projbuf overlay) */
             + (size_t)256 * 1024 * 2 + 256     /* obuf */
             + (size_t)256 * 8 + 1024;          /* stats + align slack */
  int Bc = 8;
  if      (fixed + 128 * per <= ws_size) Bc = 128;
  else if (fixed +  96 * per <= ws_size) Bc = 96;
  else if (fixed +  64 * per <= ws_size) Bc = 64;
  else if (fixed +  32 * per <= ws_size) Bc = 32;
  else if (fixed +  16 * per <= ws_size) Bc = 16;

  u8*    h8     = (u8*)alloc((size_t)Bc * 256 * 1024);      // also o_i8
  float* hsc    = (float*)alloc((size_t)Bc * 256 * 4);      // also osc
  u16*   qkvbuf = (u16*)alloc((size_t)Bc * 256 * 3072 * 2);
  u16*   projbuf= qkvbuf;                                   // OVERLAY
  u16*   obuf   = (u16*)alloc((size_t)Bc * 256 * 1024 * 2);
  float2* statsb = (float2*)alloc((size_t)Bc * 256 * 8);

  cvt_w_i8<<<768, 256, 0, stream>>>((const float*)d_in[4],  w8_d, wsc_d);
  cvt_w_i8<<<768, 256, 0, stream>>>((const float*)d_in[12], w8_t, wsc_t);
  cvt_w_i8<<<256, 256, 0, stream>>>((const float*)d_in[6],  w8o_d, wsco_d);
  cvt_w_i8<<<256, 256, 0, stream>>>((const float*)d_in[14], w8o_t, wsco_t);
  hipMemsetAsync(dp, 0, (size_t)2 * 128 * 1024 * 4, stream);

  for (int br = 0; br < 2; ++br) {
    const int F = br ? 128 : 256, logF = br ? 7 : 8, xstride = br ? 1024 : 2048;
    const float* x    = br ? target : drug;
    const float* W    = (const float*)d_in[br ? 10 : 2];
    const float* Wb   = (const float*)d_in[br ? 11 : 3];
    u8*          w8   = br ? w8_t : w8_d;
    float*       wsc  = br ? wsc_t : wsc_d;
    const float* inb  = (const float*)d_in[br ? 13 : 5];
    u8*          w8o  = br ? w8o_t : w8o_d;
    float*       wsco = br ? wsco_t : wsco_d;
    const float* outb = (const float*)d_in[br ? 15 : 7];
    const float* gg   = (const float*)d_in[br ? 16 : 8];
    const float* bb   = (const float*)d_in[br ? 17 : 9];
    float*       accp = br ? tp : dp;

    // batches per chunk (buffers hold Bc*256 rows); target rows/batch = 128
    const int nbmax = br ? (2 * Bc > 128 ? 128 : 2 * Bc) : (Bc > 128 ? 128 : Bc);

    for (int b0 = 0; b0 < 128; ) {
      int nb = nbmax;
      if (b0 + nb > 128) nb = 128 - b0;
      const int Mr = nb * F;
      hgen_i8<<<Mr / 4, 256, 0, stream>>>(x, W, Wb, h8, hsc, F, logF, b0, xstride);
      gemm_i8<false><<<dim3(3072 / 128, Mr / 256), 512, 0, stream>>>(
          h8, w8, hsc, wsc, inb, qkvbuf, nullptr, Mr, 3072, 1024);
      attn<<<8 * nb, 64 * (F / 16), 0, stream>>>(qkvbuf, obuf, F);
      quant_i8<<<Mr / 4, 256, 0, stream>>>(obuf, h8, hsc);   // h8/hsc as o8/osc
      hipMemsetAsync(statsb, 0, (size_t)Mr * 8, stream);
      gemm_i8<true><<<dim3(1024 / 128, Mr / 256), 512, 0, stream>>>(
          h8, w8o, hsc, wsco, outb, projbuf, statsb, Mr, 1024, 1024);
      ln_fin<<<(Mr + 255) / 256, 256, 0, stream>>>(statsb, Mr);
      ln_accum<<<dim3(4, F / 64, nb), 256, 0, stream>>>(projbuf, statsb, gg, bb, accp, F, b0);
      b0 += nb;
    }
  }
  cosine_sig<<<128, 256, 0, stream>>>(dp, tp, (float*)d_out);
}

// Round 14
// 535.177 us; speedup vs baseline: 1.0162x; 1.0162x over previous
//
#include <hip/hip_runtime.h>

typedef unsigned short u16;
typedef unsigned int   u32;
typedef unsigned char  u8;

using bf16x8 = __attribute__((ext_vector_type(8))) short;  // 8 bf16 in 4 VGPRs
using f32x4  = __attribute__((ext_vector_type(4))) float;
using i32x4  = __attribute__((ext_vector_type(4))) int;    // 16 i8 operand / i32 acc

__device__ __forceinline__ float bf2f(u16 h) {
  u32 u = ((u32)h) << 16;
  return __builtin_bit_cast(float, u);
}
__device__ __forceinline__ u16 f2bf(float f) {   // round-to-nearest-even
  u32 u = __builtin_bit_cast(u32, f);
  u += 0x7fffu + ((u >> 16) & 1u);
  return (u16)(u >> 16);
}

__device__ __forceinline__ void gload16(const void* src, void* ldsdst) {
  __builtin_amdgcn_global_load_lds(
      (const __attribute__((address_space(1))) void*)src,
      (__attribute__((address_space(3))) void*)ldsdst, 16, 0, 0);
}

// i8 MFMA via inline asm (ISA 10: v_mfma_i32_16x16x64_i8)
__device__ __forceinline__ void mfma_i8(i32x4& c, i32x4 a, i32x4 b) {
  asm volatile("v_mfma_i32_16x16x64_i8 %0, %1, %2, %0" : "+a"(c) : "v"(a), "v"(b));
}

// m204 bijective XCD swizzle
__device__ __forceinline__ int xcd_swz(int wg, int nwg) {
  int q = nwg >> 3, r = nwg & 7, xcd = wg & 7, loc = wg >> 3;
  return (xcd < r ? xcd * (q + 1) : r * (q + 1) + (xcd - r) * q) + loc;
}

// ---------------------------------------------------------------------------
// per-row (over K=1024) signed-i8 quantization of an f32 matrix (wave/row)
__global__ __launch_bounds__(256) void cvt_w_i8(const float* __restrict__ in,
                                                u8* __restrict__ out,
                                                float* __restrict__ sc) {
  const int row  = blockIdx.x * 4 + (threadIdx.x >> 6);
  const int lane = threadIdx.x & 63;
  const float4* p = (const float4*)(in + (size_t)row * 1024 + lane * 16);
  float v[16];
  float mx = 0.f;
#pragma unroll
  for (int i = 0; i < 4; ++i) {
    float4 t = p[i];
    v[i * 4 + 0] = t.x; v[i * 4 + 1] = t.y; v[i * 4 + 2] = t.z; v[i * 4 + 3] = t.w;
#pragma unroll
    for (int j = 0; j < 4; ++j) mx = fmaxf(mx, fabsf(v[i * 4 + j]));
  }
#pragma unroll
  for (int m = 1; m < 64; m <<= 1) mx = fmaxf(mx, __shfl_xor(mx, m));
  const float scale = mx > 0.f ? 127.f / mx : 0.f;
  u32 pk[4];
#pragma unroll
  for (int i = 0; i < 4; ++i) {
    u32 b0 = (u32)(__float2int_rn(v[i * 4 + 0] * scale) & 0xff);
    u32 b1 = (u32)(__float2int_rn(v[i * 4 + 1] * scale) & 0xff);
    u32 b2 = (u32)(__float2int_rn(v[i * 4 + 2] * scale) & 0xff);
    u32 b3 = (u32)(__float2int_rn(v[i * 4 + 3] * scale) & 0xff);
    pk[i] = b0 | (b1 << 8) | (b2 << 16) | (b3 << 24);
  }
  *(uint4*)(out + (size_t)row * 1024 + lane * 16) = make_uint4(pk[0], pk[1], pk[2], pk[3]);
  if (lane == 0) sc[row] = mx > 0.f ? mx / 127.f : 0.f;
}

// ---------------------------------------------------------------------------
// per-row signed-i8 quantization of a bf16 matrix (wave/row) — attn output
__global__ __launch_bounds__(256) void quant_i8(const u16* __restrict__ in,
                                                u8* __restrict__ out,
                                                float* __restrict__ sc) {
  const int row  = blockIdx.x * 4 + (threadIdx.x >> 6);
  const int lane = threadIdx.x & 63;
  const u16* p = in + (size_t)row * 1024 + lane * 16;
  float v[16];
  float mx = 0.f;
#pragma unroll
  for (int i = 0; i < 2; ++i) {
    bf16x8 t = *(const bf16x8*)(p + i * 8);
#pragma unroll
    for (int j = 0; j < 8; ++j) {
      float f = bf2f((u16)t[j]);
      v[i * 8 + j] = f;
      mx = fmaxf(mx, fabsf(f));
    }
  }
#pragma unroll
  for (int m = 1; m < 64; m <<= 1) mx = fmaxf(mx, __shfl_xor(mx, m));
  const float scale = mx > 0.f ? 127.f / mx : 0.f;
  u32 pk[4];
#pragma unroll
  for (int i = 0; i < 4; ++i) {
    u32 b0 = (u32)(__float2int_rn(v[i * 4 + 0] * scale) & 0xff);
    u32 b1 = (u32)(__float2int_rn(v[i * 4 + 1] * scale) & 0xff);
    u32 b2 = (u32)(__float2int_rn(v[i * 4 + 2] * scale) & 0xff);
    u32 b3 = (u32)(__float2int_rn(v[i * 4 + 3] * scale) & 0xff);
    pk[i] = b0 | (b1 << 8) | (b2 << 16) | (b3 << 24);
  }
  *(uint4*)(out + (size_t)row * 1024 + lane * 16) = make_uint4(pk[0], pk[1], pk[2], pk[3]);
  if (lane == 0) sc[row] = mx > 0.f ? mx / 127.f : 0.f;
}

// ---------------------------------------------------------------------------
// h row (1024) per wave: h = relu(x*W+b), per-row max, quantize to i8 [0,127]
__global__ __launch_bounds__(256) void hgen_i8(const float* __restrict__ x,
                                               const float* __restrict__ W,
                                               const float* __restrict__ bias,
                                               u8* __restrict__ h, float* __restrict__ hsc,
                                               int F, int logF, int b0, int xstride) {
  const int row  = blockIdx.x * 4 + (threadIdx.x >> 6);
  const int lane = threadIdx.x & 63;
  const int f = row & (F - 1);
  const int b = b0 + (row >> logF);
  const float xv = x[(size_t)b * xstride + f];
  const float4* wp = (const float4*)(W + (size_t)f * 1024 + lane * 16);
  const float4* bp = (const float4*)(bias + (size_t)f * 1024 + lane * 16);
  float hv[16];
  float mx = 0.f;
#pragma unroll
  for (int i = 0; i < 4; ++i) {
    float4 wv = wp[i];
    float4 bv = bp[i];
    hv[i * 4 + 0] = fmaxf(xv * wv.x + bv.x, 0.f);
    hv[i * 4 + 1] = fmaxf(xv * wv.y + bv.y, 0.f);
    hv[i * 4 + 2] = fmaxf(xv * wv.z + bv.z, 0.f);
    hv[i * 4 + 3] = fmaxf(xv * wv.w + bv.w, 0.f);
#pragma unroll
    for (int j = 0; j < 4; ++j) mx = fmaxf(mx, hv[i * 4 + j]);
  }
#pragma unroll
  for (int m = 1; m < 64; m <<= 1) mx = fmaxf(mx, __shfl_xor(mx, m));
  const float scale = mx > 0.f ? 127.f / mx : 0.f;
  u32 pk[4];
#pragma unroll
  for (int i = 0; i < 4; ++i) {
    u32 q0 = (u32)__float2int_rn(hv[i * 4 + 0] * scale);
    u32 q1 = (u32)__float2int_rn(hv[i * 4 + 1] * scale);
    u32 q2 = (u32)__float2int_rn(hv[i * 4 + 2] * scale);
    u32 q3 = (u32)__float2int_rn(hv[i * 4 + 3] * scale);
    pk[i] = q0 | (q1 << 8) | (q2 << 16) | (q3 << 24);
  }
  *(uint4*)(h + (size_t)row * 1024 + lane * 16) = make_uint4(pk[0], pk[1], pk[2], pk[3]);
  if (lane == 0) hsc[row] = mx > 0.f ? mx / 127.f : 0.f;
}

// ---------------------------------------------------------------------------
// i8 GEMM: C(MxN,bf16) = sA[m]*sB[n]*(qA . qB^T) + bias(N)
// 256x128 tile, BK=64 i8, 8 waves 4Mx2N, triple-buffered, counted vmcnt(3).
// STATS: atomically accumulate per-row (sum, sumsq) into stats[row].
template <bool STATS>
__global__ __launch_bounds__(512, 4) void gemm_i8(const u8* __restrict__ A,
                                                  const u8* __restrict__ B,
                                                  const float* __restrict__ sAsc,
                                                  const float* __restrict__ sBsc,
                                                  const float* __restrict__ bias,
                                                  u16* __restrict__ C,
                                                  float2* __restrict__ stats,
                                                  int M, int N, int K) {
  __shared__ u8 sA[3][256 * 64];
  __shared__ u8 sB[3][128 * 64];
  const int tid  = threadIdx.x;
  const int lane = tid & 63;
  const int w    = tid >> 6;
  const int wm   = w >> 1;
  const int wn   = w & 1;

  const int nwg = gridDim.x * gridDim.y;
  const int wg  = blockIdx.y * gridDim.x + blockIdx.x;
  const int swz = xcd_swz(wg, nwg);
  const int n0 = (swz % gridDim.x) * 128;
  const int m0 = (swz / gridDim.x) * 256;

  i32x4 acc[4][4] = {};

  const int r_in  = lane >> 2;
  const int s_src = (lane & 3) ^ ((lane >> 3) & 3);

  auto stage = [&](int kt, int b) {
    const int k0 = kt << 6;
    gload16(A + (size_t)(m0 + w * 16 + r_in) * K + k0 + s_src * 16, &sA[b][w * 1024]);
    gload16(A + (size_t)(m0 + (w + 8) * 16 + r_in) * K + k0 + s_src * 16, &sA[b][(w + 8) * 1024]);
    gload16(B + (size_t)(n0 + w * 16 + r_in) * K + k0 + s_src * 16, &sB[b][w * 1024]);
  };

  const int NT = K >> 6;
  stage(0, 0);
  stage(1, 1);
  asm volatile("s_waitcnt vmcnt(3)" ::: "memory");
  __builtin_amdgcn_s_barrier();

  int cur = 0, nx = 2;
  for (int t = 0; t < NT; ++t) {
    const bool more = (t + 2 < NT);
    if (more) stage(t + 2, nx);

    i32x4 af[4], bg[4];
    const int g = lane >> 4;
#pragma unroll
    for (int mf = 0; mf < 4; ++mf) {
      int ra = wm * 64 + mf * 16 + (lane & 15);
      af[mf] = *(const i32x4*)(&sA[cur][ra * 64 + ((g ^ ((ra >> 1) & 3)) * 16)]);
    }
#pragma unroll
    for (int nf = 0; nf < 4; ++nf) {
      int rb = wn * 64 + nf * 16 + (lane & 15);
      bg[nf] = *(const i32x4*)(&sB[cur][rb * 64 + ((g ^ ((rb >> 1) & 3)) * 16)]);
    }
    asm volatile("s_waitcnt lgkmcnt(0)" ::: "memory");
    __builtin_amdgcn_sched_barrier(0);
    __builtin_amdgcn_s_setprio(1);
#pragma unroll
    for (int mf = 0; mf < 4; ++mf)
#pragma unroll
      for (int nf = 0; nf < 4; ++nf)
        mfma_i8(acc[mf][nf], af[mf], bg[nf]);
    __builtin_amdgcn_s_setprio(0);
    if (more) asm volatile("s_waitcnt vmcnt(3)" ::: "memory");
    else      asm volatile("s_waitcnt vmcnt(0)" ::: "memory");
    __builtin_amdgcn_s_barrier();
    cur = (cur == 2) ? 0 : cur + 1;
    nx  = (nx  == 2) ? 0 : nx  + 1;
  }

  // epilogue: D layout col = lane&15, row = (lane>>4)*4 + reg; de-scale rank-1
  float sb4[4], bs4[4];
#pragma unroll
  for (int nf = 0; nf < 4; ++nf) {
    int cl = n0 + wn * 64 + nf * 16 + (lane & 15);
    sb4[nf] = sBsc[cl];
    bs4[nf] = bias[cl];
  }
#pragma unroll
  for (int mf = 0; mf < 4; ++mf) {
    int r0 = m0 + wm * 64 + mf * 16 + (lane >> 4) * 4;
    float4 sa4 = *(const float4*)(sAsc + r0);
    const float* sap = (const float*)&sa4;
#pragma unroll
    for (int reg = 0; reg < 4; ++reg) {
      float s = 0.f, s2 = 0.f;
#pragma unroll
      for (int nf = 0; nf < 4; ++nf) {
        int cl = n0 + wn * 64 + nf * 16 + (lane & 15);
        float v = (float)acc[mf][nf][reg] * (sap[reg] * sb4[nf]) + bs4[nf];
        C[(size_t)(r0 + reg) * N + cl] = f2bf(v);
        if (STATS) { s += v; s2 += v * v; }
      }
      if (STATS) {
#pragma unroll
        for (int m = 1; m < 16; m <<= 1) { s += __shfl_xor(s, m); s2 += __shfl_xor(s2, m); }
        if ((lane & 15) == 0) {
          atomicAdd(&stats[r0 + reg].x, s);
          atomicAdd(&stats[r0 + reg].y, s2);
        }
      }
    }
  }
}

// ---------------------------------------------------------------------------
// Fused attention, QBLK = F (one block per (head, batch)), NT = 64*(F/16).
// T14: K/V for tile kb+1 prefetched into registers while tile kb computes.
// Compile-time NT (rule #20): slot-1 guards fold away for NT=1024.
template <int NT>
__global__ __launch_bounds__(NT, 1) void attn(const u16* __restrict__ qkv,
                                              u16* __restrict__ o_out, int F) {
  __shared__ u16 k_lds[64 * 136];
  __shared__ u16 vT[128 * 72];        // [128 d][64+8 kpos], col-swizzled
  __shared__ u16 p_lds[16 * 16 * 72]; // per-wave [16 qrow][64+8 kpos]

  const int tid  = threadIdx.x;
  const int lane = tid & 63;
  const int w    = tid >> 6;

  const int head = blockIdx.x & 7;
  const int bc   = blockIdx.x >> 3;

  const size_t rowbase = (size_t)bc * F * 3072;
  const float scale = 0.12751744865678818f;   // log2(e)/sqrt(128)

  const int qr = lane & 15;
  const int g4 = lane >> 4;

  // Q fragments in registers: row (w*16 + qr), 16B slices kk*32+8*g4
  bf16x8 qreg[4];
  {
    const u16* qsrc = qkv + rowbase + (size_t)(w * 16 + qr) * 3072 + head * 128;
#pragma unroll
    for (int kk = 0; kk < 4; ++kk) {
      bf16x8 v = *(const bf16x8*)(qsrc + kk * 32 + 8 * g4);
#pragma unroll
      for (int j = 0; j < 8; ++j) v[j] = (short)f2bf(bf2f((u16)v[j]) * scale);
      qreg[kk] = v;
    }
  }

  // staging registers (T14 prefetch), 1 or 2 slots by NT
  bf16x8 kreg[2], va[2], vb[2];
  auto load_kv = [&](int kb) {
    const u16* ksrc = qkv + rowbase + (size_t)(kb * 64) * 3072 + 1024 + head * 128;
    const u16* vsrc = ksrc + 1024;
#pragma unroll
    for (int i = 0; i < 2; ++i) {
      int it = tid + i * NT;
      if (it < 1024) {
        int r = it >> 4, s = it & 15;
        kreg[i] = *(const bf16x8*)(ksrc + (size_t)r * 3072 + s * 8);
      }
      if (it < 512) {
        int g2 = it >> 4, s = it & 15;
        const u16* v0 = vsrc + (size_t)(2 * g2) * 3072 + s * 8;
        va[i] = *(const bf16x8*)(v0);
        vb[i] = *(const bf16x8*)(v0 + 3072);
      }
    }
  };
  auto store_kv = [&]() {
#pragma unroll
    for (int i = 0; i < 2; ++i) {
      int it = tid + i * NT;
      if (it < 1024) {
        int r = it >> 4, s = it & 15;
        *(bf16x8*)(k_lds + r * 136 + s * 8) = kreg[i];
      }
      if (it < 512) {
        int g2 = it >> 4, s = it & 15;
        int rs0 = (2 * g2) ^ ((s & 7) << 3);
        int d0  = s * 8;
#pragma unroll
        for (int j = 0; j < 8; ++j) {
          u32 pk = (u32)(u16)va[i][j] | ((u32)(u16)vb[i][j] << 16);
          *(u32*)(vT + (d0 + j) * 72 + rs0) = pk;
        }
      }
    }
  };

  f32x4 o_acc[8] = {};
  float m_run = -INFINITY, l_run = 0.f;

  load_kv(0);
  const int nkb = F >> 6;
  for (int kb = 0; kb < nkb; ++kb) {
    __syncthreads();   // prev compute done reading k_lds/vT
    store_kv();
    __syncthreads();
    if (kb + 1 < nkb) load_kv(kb + 1);   // overlaps compute below (T14)

    // S^T (64 kpos x 16 qrows): A = k rows, B = q^T (registers)
    f32x4 sa[4] = {};
#pragma unroll
    for (int kk = 0; kk < 4; ++kk) {
#pragma unroll
      for (int f = 0; f < 4; ++f) {
        bf16x8 ak = *(const bf16x8*)(k_lds + (f * 16 + qr) * 136 + kk * 32 + 8 * g4);
        sa[f] = __builtin_amdgcn_mfma_f32_16x16x32_bf16(ak, qreg[kk], sa[f], 0, 0, 0);
      }
    }

    float tmax = -INFINITY;
#pragma unroll
    for (int f = 0; f < 4; ++f)
#pragma unroll
      for (int rr = 0; rr < 4; ++rr) tmax = fmaxf(tmax, sa[f][rr]);
    tmax = fmaxf(tmax, __shfl_xor(tmax, 16));
    tmax = fmaxf(tmax, __shfl_xor(tmax, 32));

    // defer-max (T13)
    const bool ns = !__all(tmax - m_run <= 8.f);
    float mnew = m_run, alpha = 1.f;
    if (ns) { mnew = fmaxf(m_run, tmax); alpha = exp2f(m_run - mnew); }

    float psum = 0.f;
#pragma unroll
    for (int f = 0; f < 4; ++f) {
      u16 pp[4];
#pragma unroll
      for (int rr = 0; rr < 4; ++rr) {
        float p = exp2f(sa[f][rr] - mnew);
        psum += p;
        pp[rr] = f2bf(p);
      }
      uint2 u;
      u.x = (u32)pp[0] | ((u32)pp[1] << 16);
      u.y = (u32)pp[2] | ((u32)pp[3] << 16);
      *(uint2*)(p_lds + w * 1152 + qr * 72 + f * 16 + g4 * 4) = u;
    }
    psum += __shfl_xor(psum, 16);
    psum += __shfl_xor(psum, 32);
    l_run = l_run * alpha + psum;
    m_run = mnew;

    if (ns) {
#pragma unroll
      for (int rr = 0; rr < 4; ++rr) {
        float ar = __shfl(alpha, g4 * 4 + rr);
#pragma unroll
        for (int g = 0; g < 8; ++g) o_acc[g][rr] *= ar;
      }
    }

#pragma unroll
    for (int kk2 = 0; kk2 < 2; ++kk2) {
      bf16x8 pa = *(const bf16x8*)(p_lds + w * 1152 + qr * 72 + kk2 * 32 + 8 * g4);
#pragma unroll
      for (int g = 0; g < 8; ++g) {
        int swv = ((g * 2 + (qr >> 3)) & 7) << 3;
        bf16x8 vb2 = *(const bf16x8*)(vT + (g * 16 + qr) * 72 + ((kk2 * 32 + 8 * g4) ^ swv));
        o_acc[g] = __builtin_amdgcn_mfma_f32_16x16x32_bf16(pa, vb2, o_acc[g], 0, 0, 0);
      }
    }
  }

  float linv = 1.f / l_run;
#pragma unroll
  for (int rr = 0; rr < 4; ++rr) {
    float lr = __shfl(linv, g4 * 4 + rr);
    size_t row = (size_t)bc * F + w * 16 + g4 * 4 + rr;
#pragma unroll
    for (int g = 0; g < 8; ++g)
      o_out[row * 1024 + head * 128 + g * 16 + qr] = f2bf(o_acc[g][rr] * lr);
  }
}

// ---------------------------------------------------------------------------
// LN apply + column-sum; stats arrive RAW (sum, sumsq) and are finalized inline
__global__ __launch_bounds__(256) void ln_accum(const u16* __restrict__ proj,
                                                const float2* __restrict__ stats,
                                                const float* __restrict__ g,
                                                const float* __restrict__ beta,
                                                float* __restrict__ dp, int F, int b0) {
  int d  = blockIdx.x * 256 + threadIdx.x;
  int bc = blockIdx.z;
  int f0 = blockIdx.y * 64;
  const u16* base = proj + ((size_t)(bc * F + f0)) * 1024 + d;
  const float2* st = stats + bc * F + f0;
  float acc = 0.f;
  for (int f = 0; f < 64; ++f) {
    float2 s = st[f];
    float mu  = s.x * (1.f / 1024.f);
    float var = s.y * (1.f / 1024.f) - mu * mu;
    acc += (bf2f(base[(size_t)f * 1024]) - mu) * rsqrtf(var + 1e-5f);
  }
  acc = acc * g[d] + 64.f * beta[d];
  atomicAdd(&dp[(size_t)(b0 + bc) * 1024 + d], acc);
}

// ---------------------------------------------------------------------------
__global__ __launch_bounds__(256) void cosine_sig(const float* __restrict__ dp,
                                                  const float* __restrict__ tp,
                                                  float* __restrict__ out) {
  __shared__ float red[3][4];
  int b = blockIdx.x;
  int tid = threadIdx.x, lane = tid & 63, w = tid >> 6;
  float dot = 0.f, n1 = 0.f, n2 = 0.f;
  for (int i = tid; i < 1024; i += 256) {
    float a = dp[(size_t)b * 1024 + i], c = tp[(size_t)b * 1024 + i];
    dot += a * c; n1 += a * a; n2 += c * c;
  }
#pragma unroll
  for (int m = 1; m < 64; m <<= 1) {
    dot += __shfl_xor(dot, m); n1 += __shfl_xor(n1, m); n2 += __shfl_xor(n2, m);
  }
  if (lane == 0) { red[0][w] = dot; red[1][w] = n1; red[2][w] = n2; }
  __syncthreads();
  if (tid == 0) {
    dot = red[0][0] + red[0][1] + red[0][2] + red[0][3];
    n1  = red[1][0] + red[1][1] + red[1][2] + red[1][3];
    n2  = red[2][0] + red[2][1] + red[2][2] + red[2][3];
    float denom = fmaxf(sqrtf(n1) * sqrtf(n2), 1e-8f);
    out[b] = 1.f / (1.f + __expf(-dot / denom));
  }
}

// ---------------------------------------------------------------------------
extern "C" void kernel_launch(void* const* d_in, const int* in_sizes, int n_in,
                              void* d_out, int out_size, void* d_ws, size_t ws_size,
                              hipStream_t stream) {
  const float* drug   = (const float*)d_in[0];
  const float* target = (const float*)d_in[1];

  char* p = (char*)d_ws;
  auto alloc = [&](size_t bytes) -> char* {
    char* r = p; p += (bytes + 255) & ~(size_t)255; return r;
  };

  u8*    w8_d    = (u8*)alloc((size_t)3072 * 1024);
  float* wsc_d   = (float*)alloc((size_t)3072 * 4);
  u8*    w8_t    = (u8*)alloc((size_t)3072 * 1024);
  float* wsc_t   = (float*)alloc((size_t)3072 * 4);
  u8*    w8o_d   = (u8*)alloc((size_t)1024 * 1024);
  float* wsco_d  = (float*)alloc((size_t)1024 * 4);
  u8*    w8o_t   = (u8*)alloc((size_t)1024 * 1024);
  float* wsco_t  = (float*)alloc((size_t)1024 * 4);
  float* dp      = (float*)alloc((size_t)2 * 128 * 1024 * 4);
  float* tp      = dp + 128 * 1024;

  // per-batch-unit scratch (projbuf overlays qkvbuf; stream serializes)
  size_t fixed = (size_t)(p - (char*)d_ws);
  size_t per = (size_t)256 * 1024               /* h8 / o8 */
             + (size_t)256 * 4 + 256            /* hsc / osc */
             + (size_t)256 * 3072 * 2 + 256     /* qkvbuf (+projbuf overlay) */
             + (size_t)256 * 1024 * 2 + 256     /* obuf */
             + (size_t)256 * 8 + 1024;          /* stats + align slack */
  int Bc = 8;
  if      (fixed + 128 * per <= ws_size) Bc = 128;
  else if (fixed +  96 * per <= ws_size) Bc = 96;
  else if (fixed +  64 * per <= ws_size) Bc = 64;
  else if (fixed +  32 * per <= ws_size) Bc = 32;
  else if (fixed +  16 * per <= ws_size) Bc = 16;

  u8*    h8     = (u8*)alloc((size_t)Bc * 256 * 1024);      // also o_i8
  float* hsc    = (float*)alloc((size_t)Bc * 256 * 4);      // also osc
  u16*   qkvbuf = (u16*)alloc((size_t)Bc * 256 * 3072 * 2);
  u16*   projbuf= qkvbuf;                                   // OVERLAY
  u16*   obuf   = (u16*)alloc((size_t)Bc * 256 * 1024 * 2);
  float2* statsb = (float2*)alloc((size_t)Bc * 256 * 8);

  cvt_w_i8<<<768, 256, 0, stream>>>((const float*)d_in[4],  w8_d, wsc_d);
  cvt_w_i8<<<768, 256, 0, stream>>>((const float*)d_in[12], w8_t, wsc_t);
  cvt_w_i8<<<256, 256, 0, stream>>>((const float*)d_in[6],  w8o_d, wsco_d);
  cvt_w_i8<<<256, 256, 0, stream>>>((const float*)d_in[14], w8o_t, wsco_t);
  hipMemsetAsync(dp, 0, (size_t)2 * 128 * 1024 * 4, stream);

  for (int br = 0; br < 2; ++br) {
    const int F = br ? 128 : 256, logF = br ? 7 : 8, xstride = br ? 1024 : 2048;
    const float* x    = br ? target : drug;
    const float* W    = (const float*)d_in[br ? 10 : 2];
    const float* Wb   = (const float*)d_in[br ? 11 : 3];
    u8*          w8   = br ? w8_t : w8_d;
    float*       wsc  = br ? wsc_t : wsc_d;
    const float* inb  = (const float*)d_in[br ? 13 : 5];
    u8*          w8o  = br ? w8o_t : w8o_d;
    float*       wsco = br ? wsco_t : wsco_d;
    const float* outb = (const float*)d_in[br ? 15 : 7];
    const float* gg   = (const float*)d_in[br ? 16 : 8];
    const float* bb   = (const float*)d_in[br ? 17 : 9];
    float*       accp = br ? tp : dp;

    // balanced chunking: split 128 batches into equal chunks <= nbmax
    const int nbmax = br ? (2 * Bc > 128 ? 128 : 2 * Bc) : (Bc > 128 ? 128 : Bc);
    const int nch   = (128 + nbmax - 1) / nbmax;
    int nb0 = (128 + nch - 1) / nch;
    if (br) nb0 = (nb0 + 1) & ~1;              // even so Mr % 256 == 0 (F=128)

    for (int b0 = 0; b0 < 128; ) {
      int nb = nb0;
      if (b0 + nb > 128) nb = 128 - b0;
      const int Mr = nb * F;
      hgen_i8<<<Mr / 4, 256, 0, stream>>>(x, W, Wb, h8, hsc, F, logF, b0, xstride);
      gemm_i8<false><<<dim3(3072 / 128, Mr / 256), 512, 0, stream>>>(
          h8, w8, hsc, wsc, inb, qkvbuf, nullptr, Mr, 3072, 1024);
      if (br) attn<512><<<8 * nb, 512, 0, stream>>>(qkvbuf, obuf, F);
      else    attn<1024><<<8 * nb, 1024, 0, stream>>>(qkvbuf, obuf, F);
      quant_i8<<<Mr / 4, 256, 0, stream>>>(obuf, h8, hsc);   // h8/hsc as o8/osc
      hipMemsetAsync(statsb, 0, (size_t)Mr * 8, stream);
      gemm_i8<true><<<dim3(1024 / 128, Mr / 256), 512, 0, stream>>>(
          h8, w8o, hsc, wsco, outb, projbuf, statsb, Mr, 1024, 1024);
      ln_accum<<<dim3(4, F / 64, nb), 256, 0, stream>>>(projbuf, statsb, gg, bb, accp, F, b0);
      b0 += nb;
    }
  }
  cosine_sig<<<128, 256, 0, stream>>>(dp, tp, (float*)d_out);
}